// Round 1
// baseline (1697.019 us; speedup 1.0000x reference)
//
#include <hip/hip_runtime.h>
#include <hip/hip_bf16.h>

// Problem constants (from the reference)
constexpr int NU = 80000;    // users
constexpr int NI = 40000;    // items
constexpr int K  = 64;       // feature dim (== wavefront size, 1 lane per k)
constexpr int NL = 3;        // layers
constexpr int NN = NU + NI;  // 120000 nodes
constexpr int NE = 1000000;  // edges (undirected; each contributes both dirs)
constexpr float EPS   = 1e-12f;
constexpr float SLOPE = 0.01f;

// ---------------------------------------------------------------------------
// Kernel 1: e0 = l2norm(concat(Gu, Gi)); gsum[n] = rowsum(e0)
// One 64-lane wave per node, 4 waves (=4 nodes) per 256-thread block.
// ---------------------------------------------------------------------------
__global__ __launch_bounds__(256)
void norm_init_kernel(const float* __restrict__ Gu, const float* __restrict__ Gi,
                      float* __restrict__ e, float* __restrict__ gsum) {
    int node = blockIdx.x * 4 + (threadIdx.x >> 6);
    int lane = threadIdx.x & 63;
    if (node >= NN) return;
    float v = (node < NU) ? Gu[node * K + lane] : Gi[(node - NU) * K + lane];
    float ss = v * v;
    #pragma unroll
    for (int off = 32; off > 0; off >>= 1) ss += __shfl_xor(ss, off);
    float r = v / fmaxf(sqrtf(ss), EPS);
    e[node * K + lane] = r;
    float rs = r;
    #pragma unroll
    for (int off = 32; off > 0; off >>= 1) rs += __shfl_xor(rs, off);
    if (lane == 0) gsum[node] = rs;   // overwrite poison
}

// ---------------------------------------------------------------------------
// Kernel 2: symmetric scatter-add SpMM.  side[u] += x[i]; side[i] += x[u]
// One wave per edge; lane k handles feature k. Fire-and-forget f32 atomics.
// ---------------------------------------------------------------------------
__global__ __launch_bounds__(256)
void scatter_kernel(const int* __restrict__ eu, const int* __restrict__ ei,
                    const float* __restrict__ x, float* __restrict__ side) {
    int e = blockIdx.x * 4 + (threadIdx.x >> 6);
    int lane = threadIdx.x & 63;
    if (e >= NE) return;
    int u = eu[e];            // in [0, NU)
    int i = ei[e];            // in [NU, NN)
    float xu = x[u * K + lane];
    float xi = x[i * K + lane];
    atomicAdd(&side[i * K + lane], xu);
    atomicAdd(&side[u * K + lane], xi);
}

// ---------------------------------------------------------------------------
// Kernel 3: per-node NGCF layer:
//   p = side + x ; q = side * x
//   h = p @ W1 + b1 + q @ W2 + b2 ; y = l2norm(leaky_relu(h)) ; gsum[n] += rowsum(y)
// One wave per node (lane = output feature). W1,W2 staged in LDS (32 KB),
// p/q broadcast via LDS. Grid-stride over nodes to amortize the W load.
// ---------------------------------------------------------------------------
__global__ __launch_bounds__(256)
void layer_kernel(const float* __restrict__ x, const float* __restrict__ side,
                  const float* __restrict__ W1, const float* __restrict__ b1,
                  const float* __restrict__ W2, const float* __restrict__ b2,
                  float* __restrict__ y, float* __restrict__ gsum) {
    __shared__ float sW1[K * K];      // 16 KB
    __shared__ float sW2[K * K];      // 16 KB
    __shared__ float sp[4][K];
    __shared__ float sq[4][K];

    for (int t = threadIdx.x; t < K * K; t += blockDim.x) {
        sW1[t] = W1[t];
        sW2[t] = W2[t];
    }
    __syncthreads();

    const int wave = threadIdx.x >> 6;
    const int lane = threadIdx.x & 63;
    const float bias = b1[lane] + b2[lane];

    for (int node = blockIdx.x * 4 + wave; node < NN; node += gridDim.x * 4) {
        float xv = x[node * K + lane];
        float sv = side[node * K + lane];
        sp[wave][lane] = sv + xv;
        sq[wave][lane] = sv * xv;
        // same-wave LDS write->read: compiler inserts lgkmcnt ordering
        float acc = 0.f;
        #pragma unroll 8
        for (int j = 0; j < K; ++j) {
            acc = fmaf(sp[wave][j], sW1[j * K + lane], acc);
            acc = fmaf(sq[wave][j], sW2[j * K + lane], acc);
        }
        float h = acc + bias;
        h = (h > 0.f) ? h : SLOPE * h;
        float ss = h * h;
        #pragma unroll
        for (int off = 32; off > 0; off >>= 1) ss += __shfl_xor(ss, off);
        float r = h / fmaxf(sqrtf(ss), EPS);
        y[node * K + lane] = r;
        float rs = r;
        #pragma unroll
        for (int off = 32; off > 0; off >>= 1) rs += __shfl_xor(rs, off);
        if (lane == 0) gsum[node] += rs;   // one wave per node: no race
    }
}

// ---------------------------------------------------------------------------
// Kernel 4: out[n] = gsum[n] / ((L+1)*K) = gsum[n] / 256
// ---------------------------------------------------------------------------
__global__ __launch_bounds__(256)
void finalize_kernel(const float* __restrict__ gsum, float* __restrict__ out) {
    int n = blockIdx.x * blockDim.x + threadIdx.x;
    if (n < NN) out[n] = gsum[n] * (1.0f / ((NL + 1) * K));
}

extern "C" void kernel_launch(void* const* d_in, const int* in_sizes, int n_in,
                              void* d_out, int out_size, void* d_ws, size_t ws_size,
                              hipStream_t stream) {
    const float* Gu = (const float*)d_in[0];
    const float* Gi = (const float*)d_in[1];
    const float* W1 = (const float*)d_in[2];   // [NL][K][K]
    const float* b1 = (const float*)d_in[3];   // [NL][K]
    const float* W2 = (const float*)d_in[4];
    const float* b2 = (const float*)d_in[5];
    const int*  edge = (const int*)d_in[6];    // [2][NE], row 0 = users, row 1 = items
    float* out = (float*)d_out;

    // Workspace layout (f32): ebuf0 | ebuf1 | side | gsum  (~92.6 MB)
    float* ebuf0 = (float*)d_ws;
    float* ebuf1 = ebuf0 + (size_t)NN * K;
    float* side  = ebuf1 + (size_t)NN * K;
    float* gsum  = side  + (size_t)NN * K;

    const int* eu = edge;
    const int* ei = edge + NE;

    // 1. normalize initial embeddings + init gsum
    norm_init_kernel<<<(NN + 3) / 4, 256, 0, stream>>>(Gu, Gi, ebuf0, gsum);

    float* cur = ebuf0;
    float* nxt = ebuf1;
    for (int l = 0; l < NL; ++l) {
        // 2a. zero the SpMM accumulator
        hipMemsetAsync(side, 0, (size_t)NN * K * sizeof(float), stream);
        // 2b. scatter-add both edge directions
        scatter_kernel<<<(NE + 3) / 4, 256, 0, stream>>>(eu, ei, cur, side);
        // 2c. fused dense layer + activation + l2norm + rowsum accumulation
        layer_kernel<<<1024, 256, 0, stream>>>(cur, side,
                                               W1 + (size_t)l * K * K, b1 + (size_t)l * K,
                                               W2 + (size_t)l * K * K, b2 + (size_t)l * K,
                                               nxt, gsum);
        float* t = cur; cur = nxt; nxt = t;
    }

    // 3. final mean over the (L+1)*K concatenated features
    finalize_kernel<<<(NN + 255) / 256, 256, 0, stream>>>(gsum, out);
}

// Round 2
// 942.042 us; speedup vs baseline: 1.8014x; 1.8014x over previous
//
#include <hip/hip_runtime.h>
#include <hip/hip_bf16.h>

// Problem constants (from the reference)
constexpr int NU = 80000;    // users
constexpr int NI = 40000;    // items
constexpr int K  = 64;       // feature dim (== wavefront size, 1 lane per k)
constexpr int NL = 3;        // layers
constexpr int NN = NU + NI;  // 120000 nodes
constexpr int NE = 1000000;  // edges (undirected; each contributes both dirs)
constexpr float EPS   = 1e-12f;
constexpr float SLOPE = 0.01f;

constexpr int SCAN_B = 256;
constexpr int NBLK   = (NN + SCAN_B - 1) / SCAN_B;   // 469 scan blocks

// ---------------------------------------------------------------------------
// Kernel 1: e0 = l2norm(concat(Gu, Gi)); gsum[n] = rowsum(e0)
// ---------------------------------------------------------------------------
__global__ __launch_bounds__(256)
void norm_init_kernel(const float* __restrict__ Gu, const float* __restrict__ Gi,
                      float* __restrict__ e, float* __restrict__ gsum) {
    int node = blockIdx.x * 4 + (threadIdx.x >> 6);
    int lane = threadIdx.x & 63;
    if (node >= NN) return;
    float v = (node < NU) ? Gu[node * K + lane] : Gi[(node - NU) * K + lane];
    float ss = v * v;
    #pragma unroll
    for (int off = 32; off > 0; off >>= 1) ss += __shfl_xor(ss, off);
    float r = v / fmaxf(sqrtf(ss), EPS);
    e[node * K + lane] = r;
    float rs = r;
    #pragma unroll
    for (int off = 32; off > 0; off >>= 1) rs += __shfl_xor(rs, off);
    if (lane == 0) gsum[node] = rs;   // overwrite poison
}

// ---------------------------------------------------------------------------
// CSR build: histogram -> hierarchical exclusive scan -> ticket fill.
// Symmetric adjacency: edge (u,i) appends i to u's list and u to i's list.
// ---------------------------------------------------------------------------
__global__ __launch_bounds__(256)
void hist_kernel(const int* __restrict__ eu, const int* __restrict__ ei,
                 int* __restrict__ rowptr) {
    int e = blockIdx.x * blockDim.x + threadIdx.x;
    if (e >= NE) return;
    atomicAdd(&rowptr[1 + eu[e]], 1);
    atomicAdd(&rowptr[1 + ei[e]], 1);
}

// in-block inclusive scan of cnt = rowptr+1 (NN elements); bsum[b] = block total
__global__ __launch_bounds__(SCAN_B)
void scan1_kernel(int* __restrict__ cnt, int* __restrict__ bsum) {
    __shared__ int sh[SCAN_B];
    int i = blockIdx.x * SCAN_B + threadIdx.x;
    int v = (i < NN) ? cnt[i] : 0;
    sh[threadIdx.x] = v;
    __syncthreads();
    #pragma unroll
    for (int off = 1; off < SCAN_B; off <<= 1) {
        int t = (threadIdx.x >= off) ? sh[threadIdx.x - off] : 0;
        __syncthreads();
        sh[threadIdx.x] += t;
        __syncthreads();
    }
    if (i < NN) cnt[i] = sh[threadIdx.x];
    if (threadIdx.x == SCAN_B - 1) bsum[blockIdx.x] = sh[SCAN_B - 1];
}

// single-block scan of the 469 block sums -> exclusive offsets
__global__ __launch_bounds__(512)
void scan2_kernel(int* __restrict__ bsum) {
    __shared__ int sh[512];
    int v = (threadIdx.x < NBLK) ? bsum[threadIdx.x] : 0;
    sh[threadIdx.x] = v;
    __syncthreads();
    #pragma unroll
    for (int off = 1; off < 512; off <<= 1) {
        int t = (threadIdx.x >= off) ? sh[threadIdx.x - off] : 0;
        __syncthreads();
        sh[threadIdx.x] += t;
        __syncthreads();
    }
    if (threadIdx.x < NBLK) bsum[threadIdx.x] = sh[threadIdx.x] - v; // exclusive
}

// add block offsets; rowptr[0]=0 (from memset); cursor[n] = rowptr[n]
__global__ __launch_bounds__(SCAN_B)
void scan3_kernel(int* __restrict__ rowptr, const int* __restrict__ bsum,
                  int* __restrict__ cursor) {
    int i = blockIdx.x * SCAN_B + threadIdx.x;   // index into cnt = rowptr+1
    if (i < NN) {
        int v = rowptr[1 + i] + bsum[blockIdx.x];
        rowptr[1 + i] = v;                        // rowptr[i+1] final
        if (i + 1 < NN) cursor[i + 1] = v;        // start of node i+1
    }
    if (i == 0) cursor[0] = 0;
}

__global__ __launch_bounds__(256)
void fill_kernel(const int* __restrict__ eu, const int* __restrict__ ei,
                 int* __restrict__ cursor, int* __restrict__ cols) {
    int e = blockIdx.x * blockDim.x + threadIdx.x;
    if (e >= NE) return;
    int u = eu[e];
    int i = ei[e];
    int p = atomicAdd(&cursor[u], 1);
    cols[p] = i;
    int q = atomicAdd(&cursor[i], 1);
    cols[q] = u;
}

// ---------------------------------------------------------------------------
// Gather SpMM: side[n] = sum_{j in adj(n)} x[j].  One wave per node, no
// atomics, write-once. 4 accumulators keep 4 gathers in flight per wave.
// ---------------------------------------------------------------------------
__global__ __launch_bounds__(256)
void gather_kernel(const int* __restrict__ rowptr, const int* __restrict__ cols,
                   const float* __restrict__ x, float* __restrict__ side) {
    int node = blockIdx.x * 4 + (threadIdx.x >> 6);
    int lane = threadIdx.x & 63;
    if (node >= NN) return;
    int s = rowptr[node];
    int e = rowptr[node + 1];
    float a0 = 0.f, a1 = 0.f, a2 = 0.f, a3 = 0.f;
    int t = s;
    for (; t + 4 <= e; t += 4) {
        int n0 = cols[t];
        int n1 = cols[t + 1];
        int n2 = cols[t + 2];
        int n3 = cols[t + 3];
        a0 += x[(size_t)n0 * K + lane];
        a1 += x[(size_t)n1 * K + lane];
        a2 += x[(size_t)n2 * K + lane];
        a3 += x[(size_t)n3 * K + lane];
    }
    for (; t < e; ++t) a0 += x[(size_t)cols[t] * K + lane];
    side[(size_t)node * K + lane] = (a0 + a1) + (a2 + a3);
}

// ---------------------------------------------------------------------------
// Fused dense layer (unchanged from R0 — control):
//   p = side + x ; q = side * x
//   h = p@W1 + b1 + q@W2 + b2 ; y = l2norm(leaky_relu(h)) ; gsum += rowsum(y)
// ---------------------------------------------------------------------------
__global__ __launch_bounds__(256)
void layer_kernel(const float* __restrict__ x, const float* __restrict__ side,
                  const float* __restrict__ W1, const float* __restrict__ b1,
                  const float* __restrict__ W2, const float* __restrict__ b2,
                  float* __restrict__ y, float* __restrict__ gsum) {
    __shared__ float sW1[K * K];      // 16 KB
    __shared__ float sW2[K * K];      // 16 KB
    __shared__ float sp[4][K];
    __shared__ float sq[4][K];

    for (int t = threadIdx.x; t < K * K; t += blockDim.x) {
        sW1[t] = W1[t];
        sW2[t] = W2[t];
    }
    __syncthreads();

    const int wave = threadIdx.x >> 6;
    const int lane = threadIdx.x & 63;
    const float bias = b1[lane] + b2[lane];

    for (int node = blockIdx.x * 4 + wave; node < NN; node += gridDim.x * 4) {
        float xv = x[node * K + lane];
        float sv = side[node * K + lane];
        sp[wave][lane] = sv + xv;
        sq[wave][lane] = sv * xv;
        float acc = 0.f;
        #pragma unroll 8
        for (int j = 0; j < K; ++j) {
            acc = fmaf(sp[wave][j], sW1[j * K + lane], acc);
            acc = fmaf(sq[wave][j], sW2[j * K + lane], acc);
        }
        float h = acc + bias;
        h = (h > 0.f) ? h : SLOPE * h;
        float ss = h * h;
        #pragma unroll
        for (int off = 32; off > 0; off >>= 1) ss += __shfl_xor(ss, off);
        float r = h / fmaxf(sqrtf(ss), EPS);
        y[node * K + lane] = r;
        float rs = r;
        #pragma unroll
        for (int off = 32; off > 0; off >>= 1) rs += __shfl_xor(rs, off);
        if (lane == 0) gsum[node] += rs;
    }
}

// ---------------------------------------------------------------------------
// out[n] = gsum[n] / ((L+1)*K) = gsum[n] / 256
// ---------------------------------------------------------------------------
__global__ __launch_bounds__(256)
void finalize_kernel(const float* __restrict__ gsum, float* __restrict__ out) {
    int n = blockIdx.x * blockDim.x + threadIdx.x;
    if (n < NN) out[n] = gsum[n] * (1.0f / ((NL + 1) * K));
}

extern "C" void kernel_launch(void* const* d_in, const int* in_sizes, int n_in,
                              void* d_out, int out_size, void* d_ws, size_t ws_size,
                              hipStream_t stream) {
    const float* Gu = (const float*)d_in[0];
    const float* Gi = (const float*)d_in[1];
    const float* W1 = (const float*)d_in[2];   // [NL][K][K]
    const float* b1 = (const float*)d_in[3];   // [NL][K]
    const float* W2 = (const float*)d_in[4];
    const float* b2 = (const float*)d_in[5];
    const int*  edge = (const int*)d_in[6];    // [2][NE]
    float* out = (float*)d_out;

    // Workspace layout (4B elems): ebuf0 | ebuf1 | side | gsum | rowptr | bsum | cursor | cols
    // 3*7.68M + 120000 + 120001 + 512 + 120000 + 2M elems  ~= 101.8 MB
    float* ebuf0  = (float*)d_ws;
    float* ebuf1  = ebuf0 + (size_t)NN * K;
    float* side   = ebuf1 + (size_t)NN * K;
    float* gsum   = side  + (size_t)NN * K;
    int*   rowptr = (int*)(gsum + NN);
    int*   bsum   = rowptr + (NN + 1);
    int*   cursor = bsum + 512;
    int*   cols   = cursor + NN;

    const int* eu = edge;
    const int* ei = edge + NE;

    // --- CSR build (once per launch) ---
    hipMemsetAsync(rowptr, 0, (size_t)(NN + 1) * sizeof(int), stream);
    hist_kernel <<<(NE + 255) / 256, 256, 0, stream>>>(eu, ei, rowptr);
    scan1_kernel<<<NBLK, SCAN_B, 0, stream>>>(rowptr + 1, bsum);
    scan2_kernel<<<1, 512, 0, stream>>>(bsum);
    scan3_kernel<<<NBLK, SCAN_B, 0, stream>>>(rowptr, bsum, cursor);
    fill_kernel <<<(NE + 255) / 256, 256, 0, stream>>>(eu, ei, cursor, cols);

    // --- embeddings ---
    norm_init_kernel<<<(NN + 3) / 4, 256, 0, stream>>>(Gu, Gi, ebuf0, gsum);

    float* cur = ebuf0;
    float* nxt = ebuf1;
    for (int l = 0; l < NL; ++l) {
        gather_kernel<<<(NN + 3) / 4, 256, 0, stream>>>(rowptr, cols, cur, side);
        layer_kernel<<<1024, 256, 0, stream>>>(cur, side,
                                               W1 + (size_t)l * K * K, b1 + (size_t)l * K,
                                               W2 + (size_t)l * K * K, b2 + (size_t)l * K,
                                               nxt, gsum);
        float* t = cur; cur = nxt; nxt = t;
    }

    finalize_kernel<<<(NN + 255) / 256, 256, 0, stream>>>(gsum, out);
}